// Round 9
// baseline (98.889 us; speedup 1.0000x reference)
//
#include <hip/hip_runtime.h>

#define CLS   160          // CLASS_NUM * NUM_PRED
#define TOPKN 1000
#define N0 147456
#define N1 36864
#define N2 9216
#define N3 2304
#define N4 576
#define NROWS (N0 + N1 + N2 + N3)
#define BD1 N0
#define BD2 (N0 + N1)
#define BD3 (N0 + N1 + N2)
#define NSEL (4 * TOPKN + N4)
#define CAND_CAP 2048
#define KMAX 9             // max keys per thread per slice (N0/16/1024)

struct KP {
    const float *A0, *A1, *A2, *A3, *A4;
    const float *C0, *C1, *C2, *C3, *C4;
    const float *R0, *R1, *R2, *R3, *R4;
    unsigned *keys;            // [NROWS]
    unsigned *coarse;          // [4*1024]  chunk counts (chunk = key>>22)
    unsigned *fine_g;          // [4*64]    fine counts within edge chunk
    unsigned *ctl;             // [128]: done1[0..3] done2[4..7] done3[8..11]
                               //        done4[12..15]; cnt[lvl] at 32+16*lvl
    unsigned long long *cand;  // [4*CAND_CAP] composites
    unsigned *sel;             // [4*TOPKN]
    float *out;
};

__device__ __forceinline__ unsigned sortable(float f) {
    unsigned u = __float_as_uint(f);
    return (u & 0x80000000u) ? ~u : (u | 0x80000000u);
}

// ---------------------------------------------------------------------------
// K1: ruler keys (proven R4-R8 body). Zeroes coarse|fine_g|ctl (4480 words).
// The 256KB fine hist is GONE — k_mega builds everything from keys.
// ---------------------------------------------------------------------------
__global__ __launch_bounds__(256) void k_ruler(
    const float* __restrict__ c0, const float* __restrict__ c1,
    const float* __restrict__ c2, const float* __restrict__ c3,
    unsigned* __restrict__ keys, unsigned* __restrict__ zbuf)
{
    int tid = blockIdx.x * 256 + threadIdx.x;
    if (tid < 4480) zbuf[tid] = 0;

    int r0 = blockIdx.x << 7;
    const float* cb; int lr0;
    if (r0 < BD1)      { cb = c0; lr0 = r0; }
    else if (r0 < BD2) { cb = c1; lr0 = r0 - BD1; }
    else if (r0 < BD3) { cb = c2; lr0 = r0 - BD2; }
    else               { cb = c3; lr0 = r0 - BD3; }

    int wv   = threadIdx.x >> 6;
    int lane = threadIdx.x & 63;
    int sub  = lane >> 3;
    int col  = lane & 7;
    #pragma unroll
    for (int i = 0; i < 4; ++i) {
        int rrel = wv * 32 + i * 8 + sub;
        const float4* p = (const float4*)cb + (size_t)(lr0 + rrel) * 40 + col;
        float m = -3.4e38f;
        #pragma unroll
        for (int k = 0; k < 5; ++k) {
            float4 v = p[8 * k];
            m = fmaxf(m, fmaxf(fmaxf(v.x, v.y), fmaxf(v.z, v.w)));
        }
        m = fmaxf(m, __shfl_xor(m, 1));
        m = fmaxf(m, __shfl_xor(m, 2));
        m = fmaxf(m, __shfl_xor(m, 4));
        if (col == 0) keys[r0 + rrel] = sortable(m);
    }
}

// ---------------------------------------------------------------------------
// K2: everything else in ONE kernel. 64 blocks x 1024 = (level, 16 slices);
// 64 blocks <= 256 CUs => all co-resident => flag barriers are safe without
// cooperative launch. Release/acquire: syncthreads -> threadfence -> atomic
// flag; spin -> threadfence -> syncthreads (rocPRIM decoupled-lookback
// pattern; agent-scope fence does L2 wb/inv on gfx950).
// ---------------------------------------------------------------------------
__global__ __launch_bounds__(1024) void k_mega(KP p)
{
    const int b = blockIdx.x, lvl = b >> 4, slice = b & 15;
    const int t = threadIdx.x, lane = t & 63;
    const int team = t >> 8, tt = t & 255;   // 4 teams of 256 for epilogue

    __shared__ unsigned s[1024];
    __shared__ unsigned fine[64];
    __shared__ unsigned long long a[CAND_CAP];
    __shared__ float sc[4][CLS];
    __shared__ float bbx[4][8];
    __shared__ unsigned thr_s, blockcnt, gbase_s, Cstar_s, cum0_s;

    const int lbase = (lvl == 0) ? 0 : (lvl == 1) ? BD1 : (lvl == 2) ? BD2 : BD3;
    const int ln    = (lvl == 0) ? N0 : (lvl == 1) ? N1 : (lvl == 2) ? N2 : N3;
    const int ns    = ln >> 4;
    const unsigned* kp = p.keys + lbase + slice * ns;

    unsigned* done1 = p.ctl + 0;
    unsigned* done2 = p.ctl + 4;
    unsigned* done3 = p.ctl + 8;
    unsigned* done4 = p.ctl + 12;
    unsigned* cntp  = p.ctl + 32 + 16 * lvl;   // line-padded counter

    // ======== Stage A: slice chunk-hist (wave-aggregated: data lives in
    // ~2-4 hot chunks; naive LDS atomics would serialize ~9216-deep) ========
    s[t] = 0;
    if (t == 0) blockcnt = 0;
    __syncthreads();

    unsigned kreg[KMAX];
    #pragma unroll
    for (int j = 0; j < KMAX; ++j) {
        int li = j * 1024 + t;
        kreg[j] = (li < ns) ? kp[li] : 0u;
    }
    #pragma unroll
    for (int j = 0; j < KMAX; ++j) {
        int li = j * 1024 + t;
        bool valid = li < ns;
        unsigned ch = kreg[j] >> 22;
        unsigned long long todo = __ballot(valid);
        while (todo) {
            int leader = __ffsll((long long)todo) - 1;
            unsigned chl = (unsigned)__shfl((int)ch, leader);
            unsigned long long m = __ballot(valid && (ch == chl));
            if (lane == leader) atomicAdd(&s[chl], (unsigned)__popcll(m));
            todo &= ~m;
        }
    }
    __syncthreads();
    { unsigned c = s[t]; if (c) atomicAdd(&p.coarse[lvl * 1024 + t], c); }

    // ---- level-4 epilogue (no pipeline dependency — hides barrier) ----
    #pragma unroll
    for (int k = 0; k < 3; ++k) {
        int r4 = b + 64 * (team + 4 * k);
        bool act = r4 < N4;
        if (act) {
            const float* cp = p.C4 + (size_t)r4 * CLS;
            if (tt < CLS) sc[team][tt] = 1.0f / (1.0f + __expf(-cp[tt]));
            if (tt == 192) {
                const float* ap = p.A4 + (size_t)r4 * 4;
                const float* rp = p.R4 + (size_t)r4 * 8;
                float x1 = ap[0], y1 = ap[1], x2 = ap[2], y2 = ap[3];
                float w = x2 - x1 + 1.0f, h = y2 - y1 + 1.0f;
                float cx = x1 + 0.5f * w, cy = y1 + 0.5f * h;
                #pragma unroll
                for (int q = 0; q < 2; ++q) {
                    float pcx = cx + rp[4 * q + 0] * w;
                    float pcy = cy + rp[4 * q + 1] * h;
                    float pw  = w * __expf(rp[4 * q + 2]);
                    float ph  = h * __expf(rp[4 * q + 3]);
                    bbx[team][4 * q + 0] = pcx - 0.5f * pw;
                    bbx[team][4 * q + 1] = pcy - 0.5f * ph;
                    bbx[team][4 * q + 2] = pcx + 0.5f * pw;
                    bbx[team][4 * q + 3] = pcy + 0.5f * ph;
                }
            }
        }
        __syncthreads();
        if (act && tt < 240) {
            float4* orow = (float4*)(p.out + (size_t)(4 * TOPKN + r4) * 960);
            int j = tt / 3, part = tt % 3;
            float tag = (float)(j + 1);
            float4 v;
            if (part == 0)      v = make_float4(bbx[team][0], bbx[team][1], bbx[team][2], bbx[team][3]);
            else if (part == 1) v = make_float4(sc[team][j], tag, bbx[team][4], bbx[team][5]);
            else                v = make_float4(bbx[team][6], bbx[team][7], sc[team][80 + j], tag);
            orow[tt] = v;
        }
        __syncthreads();
    }

    // ======== barrier 1 ========
    __syncthreads();
    if (t == 0) {
        __threadfence(); atomicAdd(&done1[lvl], 1u);
        while (atomicAdd(&done1[lvl], 0u) < 16u) __builtin_amdgcn_s_sleep(2);
        __threadfence();
    }
    __syncthreads();

    // ======== Stage B: edge chunk from summed coarse; slice fine-hist ========
    s[t] = p.coarse[lvl * 1024 + t];
    __syncthreads();
    for (int off = 1; off < 1024; off <<= 1) {   // suffix sums
        unsigned v   = s[t];
        unsigned add = (t + off < 1024) ? s[t + off] : 0u;
        __syncthreads();
        s[t] = v + add;
        __syncthreads();
    }
    if (s[t] >= TOPKN && (t == 1023 || s[t + 1] < TOPKN)) {
        Cstar_s = (unsigned)t;
        cum0_s  = (t == 1023) ? 0u : s[t + 1];
    }
    __syncthreads();
    unsigned Cstar = Cstar_s;

    if (t < 64) fine[t] = 0;
    __syncthreads();
    #pragma unroll
    for (int j = 0; j < KMAX; ++j) {
        int li = j * 1024 + t;
        if (li < ns && (kreg[j] >> 22) == Cstar)
            atomicAdd(&fine[(kreg[j] >> 16) & 63u], 1u);   // <=~65/bin: cheap
    }
    __syncthreads();
    if (t < 64 && fine[t]) atomicAdd(&p.fine_g[lvl * 64 + t], fine[t]);

    // ======== barrier 2 ========
    __syncthreads();
    if (t == 0) {
        __threadfence(); atomicAdd(&done2[lvl], 1u);
        while (atomicAdd(&done2[lvl], 0u) < 16u) __builtin_amdgcn_s_sleep(2);
        __threadfence();
    }
    __syncthreads();

    // ======== Stage C: threshold (exact R6/R8 math) + compact ========
    if (t < 64) {
        unsigned c = p.fine_g[lvl * 64 + t];
        unsigned suf = c;
        #pragma unroll
        for (int off = 1; off < 64; off <<= 1) {
            unsigned v = __shfl_down(suf, off);
            if (t + off < 64) suf += v;
        }
        unsigned long long mask = __ballot(cum0_s + suf >= TOPKN);
        if (t == 0)
            thr_s = ((Cstar << 6) + (63u - (unsigned)__clzll(mask))) << 16;
    }
    __syncthreads();
    unsigned thr = thr_s;

    #pragma unroll
    for (int j = 0; j < KMAX; ++j) {
        int li = j * 1024 + t;
        bool pass = (li < ns) && (kreg[j] >= thr);
        unsigned long long mask = __ballot(pass);
        if (pass) {
            int leader   = __ffsll((long long)mask) - 1;
            unsigned tot = (unsigned)__popcll(mask);
            unsigned rk  = (unsigned)__popcll(mask & ((1ull << lane) - 1ull));
            unsigned wb = 0;
            if (lane == leader) wb = atomicAdd(&blockcnt, tot);  // LDS atomic
            wb = (unsigned)__shfl((int)wb, leader);
            unsigned pos = wb + rk;
            if (pos < CAND_CAP)
                a[pos] = ((unsigned long long)kreg[j] << 32) |
                         (unsigned)~(unsigned)(slice * ns + li);
        }
    }
    __syncthreads();
    unsigned bc = blockcnt; if (bc > CAND_CAP) bc = CAND_CAP;
    if (t == 0) gbase_s = atomicAdd(cntp, bc);       // ONE global atomic/block
    __syncthreads();
    unsigned gb = gbase_s;
    for (unsigned i = t; i < bc; i += 1024)
        if (gb + i < CAND_CAP) p.cand[lvl * CAND_CAP + gb + i] = a[i];

    // ======== barrier 3 ========
    __syncthreads();
    if (t == 0) {
        __threadfence(); atomicAdd(&done3[lvl], 1u);
        while (atomicAdd(&done3[lvl], 0u) < 16u) __builtin_amdgcn_s_sleep(2);
        __threadfence();
    }
    __syncthreads();

    // ======== Stage D: exact stable rank — slice 0 only ========
    if (slice == 0) {
        unsigned cntv = atomicAdd(cntp, 0u);
        if (cntv > CAND_CAP) cntv = CAND_CAP;
        for (unsigned i = t; i < cntv; i += 1024) a[i] = p.cand[lvl * CAND_CAP + i];
        __syncthreads();
        for (unsigned i = t; i < cntv; i += 1024) {
            unsigned long long mine = a[i];
            unsigned rank = 0;
            for (unsigned j2 = 0; j2 < cntv; ++j2) rank += (a[j2] > mine) ? 1u : 0u;
            if (rank < TOPKN)
                p.sel[lvl * TOPKN + rank] = ~(unsigned)(mine & 0xFFFFFFFFull);
        }
        __syncthreads();
        if (t == 0) { __threadfence(); atomicAdd(&done4[lvl], 1u); }
    }

    // ======== barrier 4: wait for rank ========
    if (t == 0) {
        while (atomicAdd(&done4[lvl], 0u) < 1u) __builtin_amdgcn_s_sleep(2);
        __threadfence();
    }
    __syncthreads();

    // ======== Stage E: epilogue for this level (16 blocks x 4 teams) ========
    const float *A = (lvl == 0) ? p.A0 : (lvl == 1) ? p.A1 : (lvl == 2) ? p.A2 : p.A3;
    const float *C = (lvl == 0) ? p.C0 : (lvl == 1) ? p.C1 : (lvl == 2) ? p.C2 : p.C3;
    const float *R = (lvl == 0) ? p.R0 : (lvl == 1) ? p.R1 : (lvl == 2) ? p.R2 : p.R3;
    for (int k = 0; k < 16; ++k) {
        int r = slice + 16 * team + 64 * k;
        bool act = r < TOPKN;
        int sidx = lvl * TOPKN + r;
        if (act) {
            int idx = (int)p.sel[sidx];
            const float* cp = C + (size_t)idx * CLS;
            if (tt < CLS) sc[team][tt] = 1.0f / (1.0f + __expf(-cp[tt]));
            if (tt == 192) {
                const float* ap = A + (size_t)idx * 4;
                const float* rp = R + (size_t)idx * 8;
                float x1 = ap[0], y1 = ap[1], x2 = ap[2], y2 = ap[3];
                float w = x2 - x1 + 1.0f, h = y2 - y1 + 1.0f;
                float cx = x1 + 0.5f * w, cy = y1 + 0.5f * h;
                #pragma unroll
                for (int q = 0; q < 2; ++q) {
                    float pcx = cx + rp[4 * q + 0] * w;
                    float pcy = cy + rp[4 * q + 1] * h;
                    float pw  = w * __expf(rp[4 * q + 2]);
                    float ph  = h * __expf(rp[4 * q + 3]);
                    bbx[team][4 * q + 0] = pcx - 0.5f * pw;
                    bbx[team][4 * q + 1] = pcy - 0.5f * ph;
                    bbx[team][4 * q + 2] = pcx + 0.5f * pw;
                    bbx[team][4 * q + 3] = pcy + 0.5f * ph;
                }
            }
        }
        __syncthreads();
        if (act && tt < 240) {
            float4* orow = (float4*)(p.out + (size_t)sidx * 960);
            int j = tt / 3, part = tt % 3;
            float tag = (float)(j + 1);
            float4 v;
            if (part == 0)      v = make_float4(bbx[team][0], bbx[team][1], bbx[team][2], bbx[team][3]);
            else if (part == 1) v = make_float4(sc[team][j], tag, bbx[team][4], bbx[team][5]);
            else                v = make_float4(bbx[team][6], bbx[team][7], sc[team][80 + j], tag);
            orow[tt] = v;
        }
        __syncthreads();
    }
}

// ---------------------------------------------------------------------------
// Workspace (uint32 words):
//   keys[195840] | coarse[4096] | fine_g[256] | ctl[128] | cand[16384] |
//   sel[4000]  (~863 KB). coarse..ctl zeroed by k_ruler each call.
// ---------------------------------------------------------------------------
extern "C" void kernel_launch(void* const* d_in, const int* in_sizes, int n_in,
                              void* d_out, int out_size, void* d_ws, size_t ws_size,
                              hipStream_t stream)
{
    bool interleaved = (in_sizes[1] > 1000000);
    const float *A[5], *C[5], *R[5];
    for (int i = 0; i < 5; ++i) {
        if (interleaved) {
            A[i] = (const float*)d_in[3 * i + 0];
            C[i] = (const float*)d_in[3 * i + 1];
            R[i] = (const float*)d_in[3 * i + 2];
        } else {
            A[i] = (const float*)d_in[i];
            C[i] = (const float*)d_in[5 + i];
            R[i] = (const float*)d_in[10 + i];
        }
    }

    unsigned* keys   = (unsigned*)d_ws;
    unsigned* coarse = keys + NROWS;
    unsigned* fine_g = coarse + 4 * 1024;
    unsigned* ctl    = fine_g + 4 * 64;
    unsigned long long* cand = (unsigned long long*)(ctl + 128);
    unsigned* sel    = (unsigned*)(cand + 4 * CAND_CAP);

    KP p;
    p.A0 = A[0]; p.A1 = A[1]; p.A2 = A[2]; p.A3 = A[3]; p.A4 = A[4];
    p.C0 = C[0]; p.C1 = C[1]; p.C2 = C[2]; p.C3 = C[3]; p.C4 = C[4];
    p.R0 = R[0]; p.R1 = R[1]; p.R2 = R[2]; p.R3 = R[3]; p.R4 = R[4];
    p.keys = keys; p.coarse = coarse; p.fine_g = fine_g; p.ctl = ctl;
    p.cand = cand; p.sel = sel; p.out = (float*)d_out;

    k_ruler<<<1530, 256, 0, stream>>>(C[0], C[1], C[2], C[3], keys, coarse);
    k_mega<<<64, 1024, 0, stream>>>(p);
}

// Round 10
// 90.056 us; speedup vs baseline: 1.0981x; 1.0981x over previous
//
#include <hip/hip_runtime.h>

#define CLS   160          // CLASS_NUM * NUM_PRED
#define TOPKN 1000
#define N0 147456
#define N1 36864
#define N2 9216
#define N3 2304
#define N4 576
#define NROWS (N0 + N1 + N2 + N3)
#define BD1 N0
#define BD2 (N0 + N1)
#define BD3 (N0 + N1 + N2)
#define NSEL (4 * TOPKN + N4)
#define NBINS 65536
#define CAND_CAP 2048

__device__ __forceinline__ unsigned sortable(float f) {
    unsigned u = __float_as_uint(f);
    return (u & 0x80000000u) ? ~u : (u | 0x80000000u);
}

// ---------------------------------------------------------------------------
// K1: ruler keys (proven R4-R9). Zeroes hist|coarse|ctrl (contiguous 266248
// words <= 391680 threads).
// ---------------------------------------------------------------------------
__global__ __launch_bounds__(256) void k_ruler(
    const float* __restrict__ c0, const float* __restrict__ c1,
    const float* __restrict__ c2, const float* __restrict__ c3,
    unsigned* __restrict__ keys, unsigned* __restrict__ hist)
{
    int tid = blockIdx.x * 256 + threadIdx.x;
    if (tid < 4 * NBINS + 4096 + 8) hist[tid] = 0;

    int r0 = blockIdx.x << 7;
    const float* cb; int lr0;
    if (r0 < BD1)      { cb = c0; lr0 = r0; }
    else if (r0 < BD2) { cb = c1; lr0 = r0 - BD1; }
    else if (r0 < BD3) { cb = c2; lr0 = r0 - BD2; }
    else               { cb = c3; lr0 = r0 - BD3; }

    int wv   = threadIdx.x >> 6;
    int lane = threadIdx.x & 63;
    int sub  = lane >> 3;
    int col  = lane & 7;
    #pragma unroll
    for (int i = 0; i < 4; ++i) {
        int rrel = wv * 32 + i * 8 + sub;
        const float4* p = (const float4*)cb + (size_t)(lr0 + rrel) * 40 + col;
        float m = -3.4e38f;
        #pragma unroll
        for (int k = 0; k < 5; ++k) {
            float4 v = p[8 * k];
            m = fmaxf(m, fmaxf(fmaxf(v.x, v.y), fmaxf(v.z, v.w)));
        }
        m = fmaxf(m, __shfl_xor(m, 1));
        m = fmaxf(m, __shfl_xor(m, 2));
        m = fmaxf(m, __shfl_xor(m, 4));
        if (col == 0) keys[r0 + rrel] = sortable(m);
    }
}

// ---------------------------------------------------------------------------
// K2: chunked segment histogram (proven R4/R6 shape) + coarse chunk sums.
// 1024 blocks x 256.
// ---------------------------------------------------------------------------
__global__ __launch_bounds__(256) void k_hist(const unsigned* __restrict__ keys,
                                              unsigned* __restrict__ hist,
                                              unsigned* __restrict__ coarse)
{
    int b        = blockIdx.x;
    int level    = b >> 8;
    unsigned seg = (b >> 4) & 15;
    int chunk    = b & 15;
    __shared__ unsigned cnt[4096];
    for (int i = threadIdx.x; i < 4096; i += 256) cnt[i] = 0;
    __syncthreads();
    int base, n;
    switch (level) {
        case 0:  base = 0;   n = N0; break;
        case 1:  base = BD1; n = N1; break;
        case 2:  base = BD2; n = N2; break;
        default: base = BD3; n = N3; break;
    }
    int q = n >> 4;
    const uint4* kp = (const uint4*)(keys + base + chunk * q);
    int nv = q >> 2;
    for (int i = threadIdx.x; i < nv; i += 256) {
        uint4 k = kp[i];
        unsigned b0 = k.x >> 16, b1 = k.y >> 16, b2 = k.z >> 16, b3 = k.w >> 16;
        if ((b0 >> 12) == seg) atomicAdd(&cnt[b0 & 4095u], 1u);
        if ((b1 >> 12) == seg) atomicAdd(&cnt[b1 & 4095u], 1u);
        if ((b2 >> 12) == seg) atomicAdd(&cnt[b2 & 4095u], 1u);
        if ((b3 >> 12) == seg) atomicAdd(&cnt[b3 & 4095u], 1u);
    }
    __syncthreads();
    unsigned* h = hist + level * NBINS + (seg << 12);
    for (int i = threadIdx.x; i < 4096; i += 256) {
        unsigned c = cnt[i];
        if (c) atomicAdd(&h[i], c);
    }
    if (threadIdx.x < 64) {
        int j = threadIdx.x;
        unsigned s2 = 0;
        #pragma unroll 8
        for (int i = 0; i < 64; ++i) s2 += cnt[j * 64 + ((i + j) & 63)];
        if (s2) atomicAdd(&coarse[level * 1024 + (int)(seg << 6) + j], s2);
    }
}

// ---------------------------------------------------------------------------
// K3: STANDALONE fast decide, 4 blocks x 1024. R6-proven coarse math:
// coalesced coarse load -> LDS suffix scan -> edge chunk; wave 0 refines
// with one coalesced 64-bin hist load + shuffle suffix-sum + ballot.
// Writes threshold to ctrl[level] for the (R4-proven-fast) consumer kernels.
// ---------------------------------------------------------------------------
__global__ __launch_bounds__(1024) void k_decide(const unsigned* __restrict__ hist,
                                                 const unsigned* __restrict__ coarse,
                                                 unsigned* __restrict__ ctrl)
{
    int level = blockIdx.x;
    int t     = threadIdx.x;
    __shared__ unsigned s[1024];
    __shared__ unsigned chunk_s, cum0_s;

    s[t] = coarse[level * 1024 + t];
    __syncthreads();
    for (int off = 1; off < 1024; off <<= 1) {
        unsigned v   = s[t];
        unsigned add = (t + off < 1024) ? s[t + off] : 0u;
        __syncthreads();
        s[t] = v + add;
        __syncthreads();
    }
    if (s[t] >= TOPKN && (t == 1023 || s[t + 1] < TOPKN)) {
        chunk_s = (unsigned)t;
        cum0_s  = (t == 1023) ? 0u : s[t + 1];
    }
    __syncthreads();
    if (t < 64) {
        const unsigned* h = hist + level * NBINS;
        unsigned c = h[chunk_s * 64 + (unsigned)t];
        unsigned suf = c;
        #pragma unroll
        for (int off = 1; off < 64; off <<= 1) {
            unsigned v = __shfl_down(suf, off);
            if (t + off < 64) suf += v;
        }
        unsigned long long mask = __ballot(cum0_s + suf >= TOPKN);
        if (t == 0)
            ctrl[level] = ((chunk_s << 6) + (63u - (unsigned)__clzll(mask))) << 16;
    }
}

// ---------------------------------------------------------------------------
// K4: compact — R4's proven-fast version, verbatim. 765 blocks x 256,
// consumes the precomputed scalar threshold; wave-aggregated append.
// ---------------------------------------------------------------------------
__global__ __launch_bounds__(256) void k_compact(const unsigned* __restrict__ keys,
                                                 unsigned* __restrict__ ctrl,
                                                 uint2* __restrict__ cand)
{
    int w = blockIdx.x * 256 + threadIdx.x;
    int lane = threadIdx.x & 63;
    int level, base;
    if (w < BD1)      { level = 0; base = 0;   }
    else if (w < BD2) { level = 1; base = BD1; }
    else if (w < BD3) { level = 2; base = BD2; }
    else              { level = 3; base = BD3; }
    unsigned key = keys[w];
    bool pass = key >= ctrl[level];
    unsigned long long mask = __ballot(pass);
    if (pass) {
        int leader    = __ffsll((long long)mask) - 1;
        unsigned tot  = (unsigned)__popcll(mask);
        unsigned rank = (unsigned)__popcll(mask & ((1ull << lane) - 1ull));
        unsigned bpos = 0;
        if (lane == leader) bpos = atomicAdd(&ctrl[4 + level], tot);
        bpos = (unsigned)__shfl((int)bpos, leader);
        unsigned pos = bpos + rank;
        if (pos < CAND_CAP)
            cand[level * CAND_CAP + pos] = make_uint2(key, (unsigned)(w - base));
    }
}

// ---------------------------------------------------------------------------
// K5: exact stable rank (R4 verbatim). 4 blocks x 1024.
// ---------------------------------------------------------------------------
__global__ __launch_bounds__(1024) void k_rank(const uint2* __restrict__ cand,
                                               const unsigned* __restrict__ ctrl,
                                               unsigned* __restrict__ sel)
{
    int level = blockIdx.x;
    unsigned cnt = ctrl[4 + level];
    if (cnt > CAND_CAP) cnt = CAND_CAP;
    __shared__ unsigned long long a[CAND_CAP];
    for (int i = threadIdx.x; i < (int)cnt; i += 1024) {
        uint2 c = cand[level * CAND_CAP + i];
        a[i] = ((unsigned long long)c.x << 32) | (unsigned)(~c.y);
    }
    __syncthreads();
    for (int i = threadIdx.x; i < (int)cnt; i += 1024) {
        unsigned long long mine = a[i];
        unsigned rank = 0;
        for (int j = 0; j < (int)cnt; ++j) rank += (a[j] > mine) ? 1u : 0u;
        if (rank < TOPKN)
            sel[level * TOPKN + rank] = ~(unsigned)(mine & 0xFFFFFFFFull);
    }
}

// ---------------------------------------------------------------------------
// K6: epilogue (proven, unchanged). One block per selected anchor.
// ---------------------------------------------------------------------------
__global__ __launch_bounds__(256) void k_epilogue(
    const float* a0, const float* a1, const float* a2, const float* a3, const float* a4,
    const float* c0, const float* c1, const float* c2, const float* c3, const float* c4,
    const float* r0, const float* r1, const float* r2, const float* r3, const float* r4,
    const unsigned* __restrict__ sel, float* __restrict__ out)
{
    int s = blockIdx.x;
    int level, idx;
    if (s < 4 * TOPKN) {
        level = s / TOPKN;
        idx   = (int)sel[s];
    } else {
        level = 4;
        idx   = s - 4 * TOPKN;
    }
    const float *A, *C, *R;
    switch (level) {
        case 0: A = a0; C = c0; R = r0; break;
        case 1: A = a1; C = c1; R = r1; break;
        case 2: A = a2; C = c2; R = r2; break;
        case 3: A = a3; C = c3; R = r3; break;
        default: A = a4; C = c4; R = r4; break;
    }

    __shared__ float sc[CLS];
    __shared__ float bb[8];

    const float* cp = C + (size_t)idx * CLS;
    if (threadIdx.x < CLS) {
        float x = cp[threadIdx.x];
        sc[threadIdx.x] = 1.0f / (1.0f + __expf(-x));
    }
    if (threadIdx.x == 192) {
        const float* ap = A + (size_t)idx * 4;
        const float* rp = R + (size_t)idx * 8;
        float x1 = ap[0], y1 = ap[1], x2 = ap[2], y2 = ap[3];
        float w  = x2 - x1 + 1.0f, h = y2 - y1 + 1.0f;
        float cx = x1 + 0.5f * w,  cy = y1 + 0.5f * h;
        #pragma unroll
        for (int p = 0; p < 2; ++p) {
            float pcx = cx + rp[4 * p + 0] * w;
            float pcy = cy + rp[4 * p + 1] * h;
            float pw  = w * __expf(rp[4 * p + 2]);
            float ph  = h * __expf(rp[4 * p + 3]);
            bb[4 * p + 0] = pcx - 0.5f * pw;
            bb[4 * p + 1] = pcy - 0.5f * ph;
            bb[4 * p + 2] = pcx + 0.5f * pw;
            bb[4 * p + 3] = pcy + 0.5f * ph;
        }
    }
    __syncthreads();

    float4* orow = (float4*)(out + (size_t)s * 960);
    if (threadIdx.x < 240) {
        int j = threadIdx.x / 3, part = threadIdx.x % 3;
        float tag = (float)(j + 1);
        float4 v;
        if (part == 0)      v = make_float4(bb[0], bb[1], bb[2], bb[3]);
        else if (part == 1) v = make_float4(sc[j], tag, bb[4], bb[5]);
        else                v = make_float4(bb[6], bb[7], sc[80 + j], tag);
        orow[threadIdx.x] = v;
    }
}

// ---------------------------------------------------------------------------
// Workspace (uint32 words):
//   keys[NROWS] | hist[4*NBINS] | coarse[4096] | ctrl[8] | cand[4*CAND_CAP]
//   (uint2) | sel[4*TOPKN]. hist|coarse|ctrl zeroed by k_ruler each call.
// ---------------------------------------------------------------------------
extern "C" void kernel_launch(void* const* d_in, const int* in_sizes, int n_in,
                              void* d_out, int out_size, void* d_ws, size_t ws_size,
                              hipStream_t stream)
{
    bool interleaved = (in_sizes[1] > 1000000);
    const float *A[5], *C[5], *R[5];
    for (int i = 0; i < 5; ++i) {
        if (interleaved) {
            A[i] = (const float*)d_in[3 * i + 0];
            C[i] = (const float*)d_in[3 * i + 1];
            R[i] = (const float*)d_in[3 * i + 2];
        } else {
            A[i] = (const float*)d_in[i];
            C[i] = (const float*)d_in[5 + i];
            R[i] = (const float*)d_in[10 + i];
        }
    }

    unsigned* keys   = (unsigned*)d_ws;
    unsigned* hist   = keys + NROWS;
    unsigned* coarse = hist + 4 * NBINS;
    unsigned* ctrl   = coarse + 4096;
    uint2*    cand   = (uint2*)(ctrl + 8);
    unsigned* sel    = (unsigned*)(cand + 4 * CAND_CAP);

    k_ruler<<<1530, 256, 0, stream>>>(C[0], C[1], C[2], C[3], keys, hist);
    k_hist<<<1024, 256, 0, stream>>>(keys, hist, coarse);
    k_decide<<<4, 1024, 0, stream>>>(hist, coarse, ctrl);
    k_compact<<<NROWS / 256, 256, 0, stream>>>(keys, ctrl, cand);
    k_rank<<<4, 1024, 0, stream>>>(cand, ctrl, sel);
    k_epilogue<<<NSEL, 256, 0, stream>>>(A[0], A[1], A[2], A[3], A[4],
                                         C[0], C[1], C[2], C[3], C[4],
                                         R[0], R[1], R[2], R[3], R[4],
                                         sel, (float*)d_out);
}